// Round 1
// baseline (1339.477 us; speedup 1.0000x reference)
//
#include <hip/hip_runtime.h>
#include <hip/hip_bf16.h>
#include <math.h>

#define N_NODES 100000
#define N_EDGES 1600000
#define FIN 14
#define H 64
#define NB 105
#define S_CNT 10000
#define LG_J 216

// ---------------- degree ----------------
__global__ __launch_bounds__(256) void deg_kernel(const int* __restrict__ dst,
                                                  int* __restrict__ deg) {
    int e = blockIdx.x * 256 + threadIdx.x;   // grid exact: 6250*256 = 1.6M
    atomicAdd(&deg[dst[e]], 1);
}

__global__ __launch_bounds__(256) void stem_kernel(const int* __restrict__ idx,
                                                   float* __restrict__ stem01) {
    int i = blockIdx.x * 256 + threadIdx.x;
    if (i < S_CNT) stem01[idx[i]] = 1.0f;
}

__global__ __launch_bounds__(256) void dis_kernel(const int* __restrict__ deg,
                                                  float* __restrict__ dis) {
    int i = blockIdx.x * 256 + threadIdx.x;
    if (i < N_NODES) dis[i] = rsqrtf((float)deg[i] + 1.0f);  // +1 self loop
}

// ---------------- xw1 = [x, stem] @ W1  (K=15) ----------------
__global__ __launch_bounds__(256) void xw1_kernel(const float* __restrict__ x,
                                                  const float* __restrict__ stem01,
                                                  const float* __restrict__ W1,
                                                  float* __restrict__ xw) {
    __shared__ __align__(16) float W1s[15 * 64];
    __shared__ __align__(16) float xs[4][16];
    int tid = threadIdx.x;
    for (int i = tid; i < 960; i += 256) W1s[i] = W1[i];
    int n0 = blockIdx.x * 4;                     // grid exact: 25000*4 = 100000
    if (tid < 60) {
        int r = tid / 15, k = tid % 15;
        int n = n0 + r;
        xs[r][k] = (k < FIN) ? x[n * FIN + k] : stem01[n];
    }
    __syncthreads();
    int r = tid >> 6, f = tid & 63;
    float acc = 0.f;
#pragma unroll
    for (int k = 0; k < 15; k++) acc += xs[r][k] * W1s[k * 64 + f];
    xw[(n0 + r) * 64 + f] = acc;
}

// ---------------- edge aggregation: one wave per edge ----------------
__global__ __launch_bounds__(256) void agg_kernel(const float* __restrict__ xw,
                                                  const int* __restrict__ src,
                                                  const int* __restrict__ dst,
                                                  const float* __restrict__ dis,
                                                  float* __restrict__ agg) {
    int idx = blockIdx.x * 256 + threadIdx.x;    // grid exact: 400000*256 = E*64
    int e = idx >> 6;
    int f = threadIdx.x & 63;
    int s = src[e], d = dst[e];
    float nv = dis[s] * dis[d];
    atomicAdd(&agg[d * 64 + f], xw[s * 64 + f] * nv);
}

// ---------------- epilogue: h = relu(agg + xw*dis^2 + b) * drop ----------------
__global__ __launch_bounds__(256) void epilogue_kernel(float* __restrict__ agg,
                                                       const float* __restrict__ xw,
                                                       const float* __restrict__ dis,
                                                       const float* __restrict__ bias,
                                                       const float* __restrict__ drop) {
    int idx = blockIdx.x * 256 + threadIdx.x;    // grid exact: 6250*256 = N*16
    int n = idx >> 4, fq = idx & 15;
    int base = n * 64 + fq * 4;
    float ds = dis[n];
    float d2 = ds * ds;
    float4 a = *(const float4*)&agg[base];
    float4 xv = *(const float4*)&xw[base];
    float4 dr = *(const float4*)&drop[base];
    float4 b = *(const float4*)&bias[fq * 4];
    float4 r;
    r.x = fmaxf(a.x + xv.x * d2 + b.x, 0.f) * dr.x;
    r.y = fmaxf(a.y + xv.y * d2 + b.y, 0.f) * dr.y;
    r.z = fmaxf(a.z + xv.z * d2 + b.z, 0.f) * dr.z;
    r.w = fmaxf(a.w + xv.w * d2 + b.w, 0.f) * dr.w;
    *(float4*)&agg[base] = r;
}

// ---------------- xw2 = h1 @ W2  (64x64), 64 nodes/block ----------------
__global__ __launch_bounds__(256) void xw2_kernel(const float* __restrict__ h,
                                                  const float* __restrict__ W2,
                                                  float* __restrict__ xw) {
    __shared__ __align__(16) float W2s[64 * 64];     // 16 KB
    __shared__ __align__(16) float hsT[64 * 68];     // k-major, pad 68: 17 KB
    int tid = threadIdx.x;
    for (int i = tid; i < 4096; i += 256) W2s[i] = W2[i];
    int n0 = blockIdx.x * 64;                        // grid 1563, tail guarded
    for (int i = tid; i < 4096; i += 256) {
        int m = i >> 6, k = i & 63;
        int n = n0 + m;
        hsT[k * 68 + m] = (n < N_NODES) ? h[n * 64 + k] : 0.f;
    }
    __syncthreads();
    int fg = tid & 15, mg = tid >> 4;
    int f0 = fg * 4, m0 = mg * 4;
    float acc[4][4];
#pragma unroll
    for (int i = 0; i < 4; i++)
#pragma unroll
        for (int j = 0; j < 4; j++) acc[i][j] = 0.f;
    for (int k = 0; k < 64; k++) {
        float4 w = *(const float4*)&W2s[k * 64 + f0];
        float4 hv = *(const float4*)&hsT[k * 68 + m0];
        float hh[4] = {hv.x, hv.y, hv.z, hv.w};
#pragma unroll
        for (int i = 0; i < 4; i++) {
            acc[i][0] += hh[i] * w.x;
            acc[i][1] += hh[i] * w.y;
            acc[i][2] += hh[i] * w.z;
            acc[i][3] += hh[i] * w.w;
        }
    }
#pragma unroll
    for (int i = 0; i < 4; i++) {
        int n = n0 + m0 + i;
        if (n < N_NODES) {
            float4 r = make_float4(acc[i][0], acc[i][1], acc[i][2], acc[i][3]);
            *(float4*)&xw[n * 64 + f0] = r;
        }
    }
}

// ---------------- logits: h2 @ [Wb|Ws] (64 x 210), 32 nodes/block ----------------
__global__ __launch_bounds__(256) void logits_kernel(const float* __restrict__ h2,
                                                     const float* __restrict__ Wb,
                                                     const float* __restrict__ bb,
                                                     const float* __restrict__ Ws,
                                                     const float* __restrict__ bs,
                                                     float* __restrict__ outb,
                                                     float* __restrict__ outs) {
    __shared__ __align__(16) float Wall[64 * LG_J];  // 55296 B (J padded to 216)
    __shared__ __align__(16) float hT[64 * 32];      // 8192 B, k-major
    int tid = threadIdx.x;
    int n0 = blockIdx.x * 32;                        // grid exact: 3125*32 = 100000
    for (int i = tid; i < 64 * LG_J; i += 256) {
        int k = i / LG_J, j = i - k * LG_J;
        float w = 0.f;
        if (j < NB) w = Wb[k * NB + j];
        else if (j < 2 * NB) w = Ws[k * NB + (j - NB)];
        Wall[i] = w;
    }
    for (int i = tid; i < 2048; i += 256) {
        int m = i >> 6, k = i & 63;
        hT[k * 32 + m] = h2[(n0 + m) * 64 + k];
    }
    __syncthreads();
    if (tid < 216) {
        int tj = tid % 27, tm = tid / 27;   // 27 j-groups x 8 m-groups
        int j0 = tj * 8, m0 = tm * 4;
        float acc[8][4];
#pragma unroll
        for (int a = 0; a < 8; a++)
#pragma unroll
            for (int b = 0; b < 4; b++) acc[a][b] = 0.f;
        for (int k = 0; k < 64; k++) {
            float4 w0 = *(const float4*)&Wall[k * LG_J + j0];
            float4 w1 = *(const float4*)&Wall[k * LG_J + j0 + 4];
            float4 hv = *(const float4*)&hT[k * 32 + m0];
            float wv[8] = {w0.x, w0.y, w0.z, w0.w, w1.x, w1.y, w1.z, w1.w};
            float hh[4] = {hv.x, hv.y, hv.z, hv.w};
#pragma unroll
            for (int a = 0; a < 8; a++)
#pragma unroll
                for (int b = 0; b < 4; b++) acc[a][b] += wv[a] * hh[b];
        }
#pragma unroll
        for (int a = 0; a < 8; a++) {
            int j = j0 + a;
            if (j < NB) {
                float bias = bb[j];
#pragma unroll
                for (int b = 0; b < 4; b++)
                    outb[(n0 + m0 + b) * NB + j] = acc[a][b] + bias;
            } else if (j < 2 * NB) {
                int jj = j - NB;
                float bias = bs[jj];
#pragma unroll
                for (int b = 0; b < 4; b++)
                    outs[(n0 + m0 + b) * NB + jj] = acc[a][b] + bias;
            }
        }
    }
}

// ---------------- gumbel softmax: one wave per (node, head) ----------------
__global__ __launch_bounds__(256) void softmax_kernel(const float* __restrict__ logits_all,
                                                      const float* __restrict__ gb,
                                                      const float* __restrict__ gs,
                                                      float* __restrict__ out_all) {
    int wid = (blockIdx.x * 256 + threadIdx.x) >> 6;  // grid exact: 50000*4 = 200000
    int lane = threadIdx.x & 63;
    int head = wid & 1;
    int n = wid >> 1;
    const float* lg = logits_all + (size_t)head * (N_NODES * NB) + (size_t)n * NB;
    const float* g = (head ? gs : gb) + (size_t)n * NB;
    float z1 = -INFINITY, z2 = -INFINITY;
    if (lane < NB) z1 = lg[lane] + g[lane];
    int l2i = lane + 64;
    if (l2i < NB) z2 = lg[l2i] + g[l2i];
    float m = fmaxf(z1, z2);
#pragma unroll
    for (int off = 32; off; off >>= 1) m = fmaxf(m, __shfl_xor(m, off));
    float e1 = (lane < NB) ? __expf(z1 - m) : 0.f;
    float e2 = (l2i < NB) ? __expf(z2 - m) : 0.f;
    float s = e1 + e2;
#pragma unroll
    for (int off = 32; off; off >>= 1) s += __shfl_xor(s, off);
    float inv = 1.f / s;
    float* o = out_all + (size_t)(2 + head) * (N_NODES * NB) + (size_t)n * NB;
    if (lane < NB) o[lane] = e1 * inv;
    if (l2i < NB) o[l2i] = e2 * inv;
}

extern "C" void kernel_launch(void* const* d_in, const int* in_sizes, int n_in,
                              void* d_out, int out_size, void* d_ws, size_t ws_size,
                              hipStream_t stream) {
    const float* x     = (const float*)d_in[0];
    const float* W1    = (const float*)d_in[1];
    const float* b1    = (const float*)d_in[2];
    const float* W2    = (const float*)d_in[3];
    const float* b2    = (const float*)d_in[4];
    const float* Wb    = (const float*)d_in[5];
    const float* bb    = (const float*)d_in[6];
    const float* Ws    = (const float*)d_in[7];
    const float* bs    = (const float*)d_in[8];
    const float* drop1 = (const float*)d_in[9];
    const float* drop2 = (const float*)d_in[10];
    const float* gb    = (const float*)d_in[11];
    const float* gs    = (const float*)d_in[12];
    const int* edge    = (const int*)d_in[13];   // [2, E]
    const int* stem    = (const int*)d_in[14];   // [S]
    float* out = (float*)d_out;

    // workspace layout (floats): xw[N*64] | agg[N*64] | dis[N] | stem01[N] | deg[N]
    float* xwbuf  = (float*)d_ws;
    float* aggbuf = xwbuf + (size_t)N_NODES * 64;
    float* dis    = aggbuf + (size_t)N_NODES * 64;
    float* stem01 = dis + N_NODES;
    int*   deg    = (int*)(stem01 + N_NODES);

    const int* esrc = edge;
    const int* edst = edge + N_EDGES;

    hipMemsetAsync(deg, 0, N_NODES * sizeof(int), stream);
    hipMemsetAsync(stem01, 0, N_NODES * sizeof(float), stream);
    hipMemsetAsync(aggbuf, 0, (size_t)N_NODES * 64 * sizeof(float), stream);

    deg_kernel<<<N_EDGES / 256, 256, 0, stream>>>(edst, deg);
    stem_kernel<<<(S_CNT + 255) / 256, 256, 0, stream>>>(stem, stem01);
    dis_kernel<<<(N_NODES + 255) / 256, 256, 0, stream>>>(deg, dis);

    // layer 1
    xw1_kernel<<<N_NODES / 4, 256, 0, stream>>>(x, stem01, W1, xwbuf);
    agg_kernel<<<(N_EDGES * 64) / 256, 256, 0, stream>>>(xwbuf, esrc, edst, dis, aggbuf);
    epilogue_kernel<<<(N_NODES * 16) / 256, 256, 0, stream>>>(aggbuf, xwbuf, dis, b1, drop1);

    // layer 2 (h1 lives in aggbuf; xw2 -> xwbuf; then re-zero aggbuf)
    xw2_kernel<<<(N_NODES + 63) / 64, 256, 0, stream>>>(aggbuf, W2, xwbuf);
    hipMemsetAsync(aggbuf, 0, (size_t)N_NODES * 64 * sizeof(float), stream);
    agg_kernel<<<(N_EDGES * 64) / 256, 256, 0, stream>>>(xwbuf, esrc, edst, dis, aggbuf);
    epilogue_kernel<<<(N_NODES * 16) / 256, 256, 0, stream>>>(aggbuf, xwbuf, dis, b2, drop2);

    // heads: logits into out[0], out[1]; softmax into out[2], out[3]
    logits_kernel<<<N_NODES / 32, 256, 0, stream>>>(aggbuf, Wb, bb, Ws, bs,
                                                    out, out + (size_t)N_NODES * NB);
    softmax_kernel<<<(2 * N_NODES) / 4, 256, 0, stream>>>(out, gb, gs, out);
}

// Round 2
// 901.347 us; speedup vs baseline: 1.4861x; 1.4861x over previous
//
#include <hip/hip_runtime.h>
#include <hip/hip_bf16.h>
#include <math.h>

#define N_NODES 100000
#define N_EDGES 1600000
#define FIN 14
#define H 64
#define NB 105
#define S_CNT 10000
#define LG_J 216
#define SCAN_BLOCKS 391   // ceil(100000/256)

// ---------------- degree histogram (edges only; +1 self-loop added in dis) ----
__global__ __launch_bounds__(256) void deg_kernel(const int* __restrict__ dst,
                                                  int* __restrict__ deg) {
    int e = blockIdx.x * 256 + threadIdx.x;   // grid exact: 6250*256 = 1.6M
    atomicAdd(&deg[dst[e]], 1);
}

__global__ __launch_bounds__(256) void stem_kernel(const int* __restrict__ idx,
                                                   float* __restrict__ stem01) {
    int i = blockIdx.x * 256 + threadIdx.x;
    if (i < S_CNT) stem01[idx[i]] = 1.0f;
}

__global__ __launch_bounds__(256) void dis_kernel(const int* __restrict__ deg,
                                                  float* __restrict__ dis) {
    int i = blockIdx.x * 256 + threadIdx.x;
    if (i < N_NODES) dis[i] = rsqrtf((float)deg[i] + 1.0f);  // +1 self loop
}

// ---------------- CSR build: scan deg -> rowptr, scatter src by dst ----------
__global__ __launch_bounds__(256) void scan1_kernel(const int* __restrict__ deg,
                                                    int* __restrict__ rowptr,
                                                    int* __restrict__ bsum) {
    __shared__ int s[256];
    int t = threadIdx.x;
    int i = blockIdx.x * 256 + t;
    int v = (i < N_NODES) ? deg[i] : 0;
    s[t] = v;
    __syncthreads();
#pragma unroll
    for (int o = 1; o < 256; o <<= 1) {
        int x = (t >= o) ? s[t - o] : 0;
        __syncthreads();
        s[t] += x;
        __syncthreads();
    }
    if (i < N_NODES) rowptr[i + 1] = s[t];
    if (t == 255) bsum[blockIdx.x] = s[255];
}

__global__ __launch_bounds__(512) void scan2_kernel(const int* __restrict__ bsum,
                                                    int* __restrict__ boff) {
    __shared__ int s[512];
    int t = threadIdx.x;
    int v = (t < SCAN_BLOCKS) ? bsum[t] : 0;
    s[t] = v;
    __syncthreads();
#pragma unroll
    for (int o = 1; o < 512; o <<= 1) {
        int x = (t >= o) ? s[t - o] : 0;
        __syncthreads();
        s[t] += x;
        __syncthreads();
    }
    if (t < SCAN_BLOCKS) boff[t] = s[t] - v;   // exclusive
}

__global__ __launch_bounds__(256) void scan3_kernel(const int* __restrict__ boff,
                                                    int* __restrict__ rowptr,
                                                    int* __restrict__ cursor) {
    int t = threadIdx.x;
    int i = blockIdx.x * 256 + t;
    if (i < N_NODES) {
        int val = rowptr[i + 1] + boff[blockIdx.x];
        rowptr[i + 1] = val;
        if (i + 1 < N_NODES) cursor[i + 1] = val;
    }
    if (i == 0) { rowptr[0] = 0; cursor[0] = 0; }
}

__global__ __launch_bounds__(256) void scatter_kernel(const int* __restrict__ src,
                                                      const int* __restrict__ dst,
                                                      int* __restrict__ cursor,
                                                      int* __restrict__ col) {
    int e = blockIdx.x * 256 + threadIdx.x;   // grid exact
    int d = dst[e];
    int pos = atomicAdd(&cursor[d], 1);
    col[pos] = src[e];
}

// ---------------- xws1 = ([x, stem] @ W1) * dis  (K=15) ----------------
__global__ __launch_bounds__(256) void xw1_kernel(const float* __restrict__ x,
                                                  const float* __restrict__ stem01,
                                                  const float* __restrict__ dis,
                                                  const float* __restrict__ W1,
                                                  float* __restrict__ xws) {
    __shared__ __align__(16) float W1s[15 * 64];
    __shared__ __align__(16) float xs[4][16];
    int tid = threadIdx.x;
    for (int i = tid; i < 960; i += 256) W1s[i] = W1[i];
    int n0 = blockIdx.x * 4;                     // grid exact: 25000*4 = 100000
    if (tid < 60) {
        int r = tid / 15, k = tid % 15;
        int n = n0 + r;
        xs[r][k] = (k < FIN) ? x[n * FIN + k] : stem01[n];
    }
    __syncthreads();
    int r = tid >> 6, f = tid & 63;
    float acc = 0.f;
#pragma unroll
    for (int k = 0; k < 15; k++) acc += xs[r][k] * W1s[k * 64 + f];
    xws[(n0 + r) * 64 + f] = acc * dis[n0 + r];
}

// ---------------- CSR aggregation + fused epilogue ----------------
// acc = xws[node] + sum_{s in N(node)} xws[s];  h = relu(dis[node]*acc + b)*drop
__global__ __launch_bounds__(256) void agg_csr_kernel(const float* __restrict__ xws,
                                                      const int* __restrict__ rowptr,
                                                      const int* __restrict__ col,
                                                      const float* __restrict__ dis,
                                                      const float* __restrict__ bias,
                                                      const float* __restrict__ drop,
                                                      float* __restrict__ hout) {
    int node = (blockIdx.x * 256 + threadIdx.x) >> 6;  // grid exact: 25000*4
    int f = threadIdx.x & 63;
    int beg = rowptr[node], end = rowptr[node + 1];
    float acc0 = xws[node * 64 + f];   // self loop (already * dis[node])
    float acc1 = 0.f, acc2 = 0.f, acc3 = 0.f;
    int j = beg;
    for (; j + 4 <= end; j += 4) {
        int s0 = col[j], s1 = col[j + 1], s2 = col[j + 2], s3 = col[j + 3];
        acc0 += xws[s0 * 64 + f];
        acc1 += xws[s1 * 64 + f];
        acc2 += xws[s2 * 64 + f];
        acc3 += xws[s3 * 64 + f];
    }
    for (; j < end; j++) acc0 += xws[col[j] * 64 + f];
    float acc = (acc0 + acc1) + (acc2 + acc3);
    float r = fmaxf(fmaf(dis[node], acc, bias[f]), 0.f) * drop[node * 64 + f];
    hout[node * 64 + f] = r;
}

// ---------------- xws2 = (h1 @ W2) * dis  (64x64), in-place safe -------------
__global__ __launch_bounds__(256) void xw2_kernel(const float* __restrict__ h,
                                                  const float* __restrict__ dis,
                                                  const float* __restrict__ W2,
                                                  float* __restrict__ xws) {
    __shared__ __align__(16) float W2s[64 * 64];     // 16 KB
    __shared__ __align__(16) float hsT[64 * 68];     // k-major, pad 68: 17 KB
    int tid = threadIdx.x;
    for (int i = tid; i < 4096; i += 256) W2s[i] = W2[i];
    int n0 = blockIdx.x * 64;                        // grid 1563, tail guarded
    for (int i = tid; i < 4096; i += 256) {
        int m = i >> 6, k = i & 63;
        int n = n0 + m;
        hsT[k * 68 + m] = (n < N_NODES) ? h[n * 64 + k] : 0.f;
    }
    __syncthreads();
    int fg = tid & 15, mg = tid >> 4;
    int f0 = fg * 4, m0 = mg * 4;
    float acc[4][4];
#pragma unroll
    for (int i = 0; i < 4; i++)
#pragma unroll
        for (int j = 0; j < 4; j++) acc[i][j] = 0.f;
    for (int k = 0; k < 64; k++) {
        float4 w = *(const float4*)&W2s[k * 64 + f0];
        float4 hv = *(const float4*)&hsT[k * 68 + m0];
        float hh[4] = {hv.x, hv.y, hv.z, hv.w};
#pragma unroll
        for (int i = 0; i < 4; i++) {
            acc[i][0] += hh[i] * w.x;
            acc[i][1] += hh[i] * w.y;
            acc[i][2] += hh[i] * w.z;
            acc[i][3] += hh[i] * w.w;
        }
    }
#pragma unroll
    for (int i = 0; i < 4; i++) {
        int n = n0 + m0 + i;
        if (n < N_NODES) {
            float ds = dis[n];
            float4 r = make_float4(acc[i][0] * ds, acc[i][1] * ds,
                                   acc[i][2] * ds, acc[i][3] * ds);
            *(float4*)&xws[n * 64 + f0] = r;
        }
    }
}

// ---------------- logits: h2 @ [Wb|Ws] (64 x 210), 32 nodes/block ----------------
__global__ __launch_bounds__(256) void logits_kernel(const float* __restrict__ h2,
                                                     const float* __restrict__ Wb,
                                                     const float* __restrict__ bb,
                                                     const float* __restrict__ Ws,
                                                     const float* __restrict__ bs,
                                                     float* __restrict__ outb,
                                                     float* __restrict__ outs) {
    __shared__ __align__(16) float Wall[64 * LG_J];  // 55296 B (J padded to 216)
    __shared__ __align__(16) float hT[64 * 32];      // 8192 B, k-major
    int tid = threadIdx.x;
    int n0 = blockIdx.x * 32;                        // grid exact: 3125*32 = 100000
    for (int i = tid; i < 64 * LG_J; i += 256) {
        int k = i / LG_J, j = i - k * LG_J;
        float w = 0.f;
        if (j < NB) w = Wb[k * NB + j];
        else if (j < 2 * NB) w = Ws[k * NB + (j - NB)];
        Wall[i] = w;
    }
    for (int i = tid; i < 2048; i += 256) {
        int m = i >> 6, k = i & 63;
        hT[k * 32 + m] = h2[(n0 + m) * 64 + k];
    }
    __syncthreads();
    if (tid < 216) {
        int tj = tid % 27, tm = tid / 27;   // 27 j-groups x 8 m-groups
        int j0 = tj * 8, m0 = tm * 4;
        float acc[8][4];
#pragma unroll
        for (int a = 0; a < 8; a++)
#pragma unroll
            for (int b = 0; b < 4; b++) acc[a][b] = 0.f;
        for (int k = 0; k < 64; k++) {
            float4 w0 = *(const float4*)&Wall[k * LG_J + j0];
            float4 w1 = *(const float4*)&Wall[k * LG_J + j0 + 4];
            float4 hv = *(const float4*)&hT[k * 32 + m0];
            float wv[8] = {w0.x, w0.y, w0.z, w0.w, w1.x, w1.y, w1.z, w1.w};
            float hh[4] = {hv.x, hv.y, hv.z, hv.w};
#pragma unroll
            for (int a = 0; a < 8; a++)
#pragma unroll
                for (int b = 0; b < 4; b++) acc[a][b] += wv[a] * hh[b];
        }
#pragma unroll
        for (int a = 0; a < 8; a++) {
            int j = j0 + a;
            if (j < NB) {
                float bias = bb[j];
#pragma unroll
                for (int b = 0; b < 4; b++)
                    outb[(n0 + m0 + b) * NB + j] = acc[a][b] + bias;
            } else if (j < 2 * NB) {
                int jj = j - NB;
                float bias = bs[jj];
#pragma unroll
                for (int b = 0; b < 4; b++)
                    outs[(n0 + m0 + b) * NB + jj] = acc[a][b] + bias;
            }
        }
    }
}

// ---------------- gumbel softmax: one wave per (node, head) ----------------
__global__ __launch_bounds__(256) void softmax_kernel(const float* __restrict__ logits_all,
                                                      const float* __restrict__ gb,
                                                      const float* __restrict__ gs,
                                                      float* __restrict__ out_all) {
    int wid = (blockIdx.x * 256 + threadIdx.x) >> 6;  // grid exact: 50000*4 = 200000
    int lane = threadIdx.x & 63;
    int head = wid & 1;
    int n = wid >> 1;
    const float* lg = logits_all + (size_t)head * (N_NODES * NB) + (size_t)n * NB;
    const float* g = (head ? gs : gb) + (size_t)n * NB;
    float z1 = -INFINITY, z2 = -INFINITY;
    if (lane < NB) z1 = lg[lane] + g[lane];
    int l2i = lane + 64;
    if (l2i < NB) z2 = lg[l2i] + g[l2i];
    float m = fmaxf(z1, z2);
#pragma unroll
    for (int off = 32; off; off >>= 1) m = fmaxf(m, __shfl_xor(m, off));
    float e1 = (lane < NB) ? __expf(z1 - m) : 0.f;
    float e2 = (l2i < NB) ? __expf(z2 - m) : 0.f;
    float s = e1 + e2;
#pragma unroll
    for (int off = 32; off; off >>= 1) s += __shfl_xor(s, off);
    float inv = 1.f / s;
    float* o = out_all + (size_t)(2 + head) * (N_NODES * NB) + (size_t)n * NB;
    if (lane < NB) o[lane] = e1 * inv;
    if (l2i < NB) o[l2i] = e2 * inv;
}

extern "C" void kernel_launch(void* const* d_in, const int* in_sizes, int n_in,
                              void* d_out, int out_size, void* d_ws, size_t ws_size,
                              hipStream_t stream) {
    const float* x     = (const float*)d_in[0];
    const float* W1    = (const float*)d_in[1];
    const float* b1    = (const float*)d_in[2];
    const float* W2    = (const float*)d_in[3];
    const float* b2    = (const float*)d_in[4];
    const float* Wb    = (const float*)d_in[5];
    const float* bb    = (const float*)d_in[6];
    const float* Ws    = (const float*)d_in[7];
    const float* bs    = (const float*)d_in[8];
    const float* drop1 = (const float*)d_in[9];
    const float* drop2 = (const float*)d_in[10];
    const float* gb    = (const float*)d_in[11];
    const float* gs    = (const float*)d_in[12];
    const int* edge    = (const int*)d_in[13];   // [2, E]
    const int* stem    = (const int*)d_in[14];   // [S]
    float* out = (float*)d_out;

    // workspace (4-byte elems):
    // A[N*64] (xws1, then h2) | B[N*64] (h1, then xws2 in-place) |
    // dis[N] | stem01[N] | deg[N] | rowptr[N+1] | cursor[N] |
    // bsum[391] | boff[391] | col[E]
    float* A      = (float*)d_ws;
    float* B      = A + (size_t)N_NODES * 64;
    float* dis    = B + (size_t)N_NODES * 64;
    float* stem01 = dis + N_NODES;
    int*   deg    = (int*)(stem01 + N_NODES);
    int*   rowptr = deg + N_NODES;
    int*   cursor = rowptr + (N_NODES + 1);
    int*   bsum   = cursor + N_NODES;
    int*   boff   = bsum + SCAN_BLOCKS;
    int*   col    = boff + SCAN_BLOCKS;

    const int* esrc = edge;
    const int* edst = edge + N_EDGES;

    hipMemsetAsync(deg, 0, N_NODES * sizeof(int), stream);
    hipMemsetAsync(stem01, 0, N_NODES * sizeof(float), stream);

    deg_kernel<<<N_EDGES / 256, 256, 0, stream>>>(edst, deg);
    stem_kernel<<<(S_CNT + 255) / 256, 256, 0, stream>>>(stem, stem01);
    dis_kernel<<<SCAN_BLOCKS, 256, 0, stream>>>(deg, dis);

    // CSR build
    scan1_kernel<<<SCAN_BLOCKS, 256, 0, stream>>>(deg, rowptr, bsum);
    scan2_kernel<<<1, 512, 0, stream>>>(bsum, boff);
    scan3_kernel<<<SCAN_BLOCKS, 256, 0, stream>>>(boff, rowptr, cursor);
    scatter_kernel<<<N_EDGES / 256, 256, 0, stream>>>(esrc, edst, cursor, col);

    // layer 1: xws1 -> A; h1 -> B
    xw1_kernel<<<N_NODES / 4, 256, 0, stream>>>(x, stem01, dis, W1, A);
    agg_csr_kernel<<<(N_NODES * 64) / 256, 256, 0, stream>>>(A, rowptr, col, dis, b1, drop1, B);

    // layer 2: xws2 -> B (in-place over h1); h2 -> A
    xw2_kernel<<<(N_NODES + 63) / 64, 256, 0, stream>>>(B, dis, W2, B);
    agg_csr_kernel<<<(N_NODES * 64) / 256, 256, 0, stream>>>(B, rowptr, col, dis, b2, drop2, A);

    // heads: logits into out[0], out[1]; softmax into out[2], out[3]
    logits_kernel<<<N_NODES / 32, 256, 0, stream>>>(A, Wb, bb, Ws, bs,
                                                    out, out + (size_t)N_NODES * NB);
    softmax_kernel<<<(2 * N_NODES) / 4, 256, 0, stream>>>(out, gb, gs, out);
}